// Round 2
// baseline (1176.750 us; speedup 1.0000x reference)
//
#include <hip/hip_runtime.h>

typedef unsigned short u16;
typedef unsigned int   u32;
typedef __attribute__((ext_vector_type(8))) short bf16x8;
typedef __attribute__((ext_vector_type(4))) float f32x4;

#define NB 131072               // batch rows
#define LN_EPS 1e-5f
#define EX_STRIDE 136           // 128 + 8 pad (bf16 elems) -> 2-way bank alias only (free, m136)

__device__ __forceinline__ u16 f2b(float f){
  union { float f; u32 u; } c; c.f = f;
  u32 r = c.u + 0x7FFFu + ((c.u >> 16) & 1u);   // RNE fp32->bf16
  return (u16)(r >> 16);
}
__device__ __forceinline__ float upk(u32 pr, int hi){
  union { u32 u; float f; } c; c.u = hi ? (pr & 0xFFFF0000u) : (pr << 16); return c.f;
}
__device__ __forceinline__ float rowsum16(float x){
  // masks 1,2,4,8 stay inside the 16-lane group holding one C-layout row
  x += __shfl_xor(x, 1);
  x += __shfl_xor(x, 2);
  x += __shfl_xor(x, 4);
  x += __shfl_xor(x, 8);
  return x;
}
// 8 consecutive fp32 -> bf16x8 A-fragment chunk
__device__ __forceinline__ bf16x8 cvt8(const float* __restrict__ s){
  f32x4 x0 = *(const f32x4*)s;
  f32x4 x1 = *(const f32x4*)(s + 4);
  bf16x8 r;
  r[0]=(short)f2b(x0[0]); r[1]=(short)f2b(x0[1]);
  r[2]=(short)f2b(x0[2]); r[3]=(short)f2b(x0[3]);
  r[4]=(short)f2b(x1[0]); r[5]=(short)f2b(x1[1]);
  r[6]=(short)f2b(x1[2]); r[7]=(short)f2b(x1[3]);
  return r;
}

// 16x128 @ 128x128 GEMM: A frags (4 K-tiles) vs pre-packed B fragments in ws.
__device__ __forceinline__ void gemm16(const bf16x8 a[4], const u16* __restrict__ Bmat,
                                       int lane, f32x4 C[8]){
  const bf16x8* Bf = (const bf16x8*)Bmat;
  #pragma unroll
  for (int nt = 0; nt < 8; nt++){
    f32x4 c = {0.f, 0.f, 0.f, 0.f};
    #pragma unroll
    for (int kt = 0; kt < 4; kt++){
      bf16x8 b = Bf[(nt*4 + kt)*64 + lane];
      c = __builtin_amdgcn_mfma_f32_16x16x32_bf16(a[kt], b, c, 0, 0, 0);
    }
    C[nt] = c;
  }
}

// ---------------- prep: pack weights (fp32 -> bf16) into B-fragment order + fp32 vectors ----
// packB layout: mat m (0..11), fragment fi = nt*4+kt, lane, j:
//   packB[m*16384 + fi*512 + lane*8 + j] = Bg[k][n],  k = kt*32+(lane>>4)*8+j, n = nt*16+(lane&15)
// mats 0..5 (fwd, X @ W^T):  Bg[k][n] = src[n*128+k]
// mats 6..11 (bwd, G @ W):   Bg[k][n] = src[k*128+n]
__global__ void prep_kernel(const float* __restrict__ t,   const float* __restrict__ W_in,
                            const float* __restrict__ b_in,const float* __restrict__ fw,
                            const float* __restrict__ fb,  const float* __restrict__ gamma,
                            const float* __restrict__ beta,const float* __restrict__ Wl,
                            const float* __restrict__ bl,  const float* __restrict__ W_out,
                            const float* __restrict__ b_out,
                            u16* __restrict__ packB, float* __restrict__ vecs)
{
  int bid = blockIdx.x, tid = threadIdx.x;
  if (bid < 768){
    int e    = bid*256 + tid;       // 0..196607
    int m    = e >> 14;             // matrix 0..11
    int r    = e & 16383;
    int fi   = r >> 9;              // nt*4+kt
    int lane = (r >> 3) & 63;
    int j    = r & 7;
    int nt = fi >> 2, kt = fi & 3;
    int k = kt*32 + (lane >> 4)*8 + j;
    int n = nt*16 + (lane & 15);
    const float* src; bool tr;
    if      (m == 0){ src = W_in;              tr = true;  }
    else if (m <= 4){ src = Wl + (m-1)*16384;  tr = true;  }
    else if (m == 5){ src = W_out;             tr = true;  }
    else if (m == 6){ src = W_out;             tr = false; }
    else if (m <=10){ src = Wl + (m-7)*16384;  tr = false; }
    else            { src = W_in;              tr = false; }
    packB[e] = f2b(tr ? src[n*128 + k] : src[k*128 + n]);
  } else {
    int idx = (bid - 768)*256 + tid;   // 0..2303
    float tv = t[0];
    float v;
    if      (idx <  512) v = sinf(tv * fw[idx] + fb[idx]);
    else if (idx <  640) v = b_in[idx - 512];
    else if (idx < 1152) v = bl[idx - 640];
    else if (idx < 1664) v = gamma[idx - 1152];
    else if (idx < 2176) v = beta[idx - 1664];
    else                 v = b_out[idx - 2176];
    vecs[idx] = v;
  }
}

// ---------------- fused forward + VJP ----------------
__global__ __launch_bounds__(256, 2)
void fused_vf(const float* __restrict__ p, const float* __restrict__ w,
              const u16* __restrict__ packB, const float* __restrict__ vecs,
              float* __restrict__ dp_out, float* __restrict__ dw_out)
{
  __shared__ __align__(16) u16  exch[4 * 16 * EX_STRIDE];
  __shared__ float sv[2304];

  const int tid  = threadIdx.x;
  const int wave = tid >> 6, lane = tid & 63;
  const int l15  = lane & 15, quad = lane >> 4;
  u16* ex = exch + wave * 16 * EX_STRIDE;

  for (int idx = tid; idx < 2304; idx += 256) sv[idx] = vecs[idx];
  __syncthreads();
  const float* sS    = sv;          // [4][128] sin embed
  const float* sBin  = sv + 512;    // [128]
  const float* sBl   = sv + 640;    // [4][128]
  const float* sGam  = sv + 1152;   // [4][128]
  const float* sBet  = sv + 1664;   // [4][128]
  const float* sBout = sv + 2176;   // [128]

  const long rowBase = (long)blockIdx.x * 64 + wave * 16;

  // backward checkpoints (bf16 pairs packed along C reg dim)
  u32 sigp[4][8][2];
  u32 xhp [4][8][2];
  float invs[4][4];

  bf16x8 a[4];
  f32x4  C[8];

  // ---- forward: h0 = p @ W_in^T + b_in ----
  {
    const float* pr = p + (size_t)(rowBase + l15)*128 + quad*8;
    #pragma unroll
    for (int kt = 0; kt < 4; kt++) a[kt] = cvt8(pr + kt*32);
  }
  gemm16(a, packB + 0*16384, lane, C);
  #pragma unroll
  for (int nt = 0; nt < 8; nt++){
    float bv = sBin[nt*16 + l15];
    #pragma unroll
    for (int r = 0; r < 4; r++) C[nt][r] += bv;
  }

  // ---- forward layers ----
  #pragma unroll
  for (int i = 0; i < 4; i++){
    float sum[4] = {0,0,0,0}, ssq[4] = {0,0,0,0};
    #pragma unroll
    for (int nt = 0; nt < 8; nt++){
      float se = sS[i*128 + nt*16 + l15];
      #pragma unroll
      for (int r = 0; r < 4; r++){
        float x  = C[nt][r] + se;                 // a_i
        float e  = __expf(-fabsf(x));
        float li = __logf(1.0f + e);
        float sp = fmaxf(x, 0.0f) + li;           // softplus
        float sg = (x >= 0.0f) ? 1.0f/(1.0f + e) : e/(1.0f + e);  // sigmoid
        u16 sb = f2b(sg);
        if (r & 1) sigp[i][nt][r>>1] |= ((u32)sb) << 16; else sigp[i][nt][r>>1] = sb;
        sum[r] += sp; ssq[r] += sp*sp;
        C[nt][r] = sp;                            // u_i in place
      }
    }
    float mu[4], inv[4];
    #pragma unroll
    for (int r = 0; r < 4; r++){
      float m1 = rowsum16(sum[r]) * (1.0f/128.0f);
      float m2 = rowsum16(ssq[r]) * (1.0f/128.0f);
      float var = m2 - m1*m1;
      mu[r] = m1; inv[r] = rsqrtf(fmaxf(var, 0.0f) + LN_EPS);
      invs[i][r] = inv[r];
    }
    __syncthreads();
    #pragma unroll
    for (int nt = 0; nt < 8; nt++){
      float g_ = sGam[i*128 + nt*16 + l15];
      float b_ = sBet[i*128 + nt*16 + l15];
      #pragma unroll
      for (int r = 0; r < 4; r++){
        float xh = (C[nt][r] - mu[r]) * inv[r];
        u16 xb = f2b(xh);
        if (r & 1) xhp[i][nt][r>>1] |= ((u32)xb) << 16; else xhp[i][nt][r>>1] = xb;
        float v = xh * g_ + b_;
        ex[(quad*4 + r)*EX_STRIDE + nt*16 + l15] = f2b(v);
      }
    }
    __syncthreads();
    {
      const u16* rp = ex + l15*EX_STRIDE + quad*8;
      #pragma unroll
      for (int kt = 0; kt < 4; kt++) a[kt] = *(const bf16x8*)(rp + kt*32);
    }
    gemm16(a, packB + (1+i)*16384, lane, C);
    #pragma unroll
    for (int nt = 0; nt < 8; nt++){
      float bv = sBl[i*128 + nt*16 + l15];
      #pragma unroll
      for (int r = 0; r < 4; r++) C[nt][r] += bv;
    }
  }

  // ---- forward head: dp = h4 @ W_out^T + b_out (direct fp32 C-layout store) ----
  __syncthreads();
  #pragma unroll
  for (int nt = 0; nt < 8; nt++)
    #pragma unroll
    for (int r = 0; r < 4; r++)
      ex[(quad*4 + r)*EX_STRIDE + nt*16 + l15] = f2b(C[nt][r]);
  __syncthreads();
  {
    const u16* rp = ex + l15*EX_STRIDE + quad*8;
    #pragma unroll
    for (int kt = 0; kt < 4; kt++) a[kt] = *(const bf16x8*)(rp + kt*32);
  }
  gemm16(a, packB + 5*16384, lane, C);
  {
    float* gp = dp_out + (size_t)rowBase*128;
    #pragma unroll
    for (int nt = 0; nt < 8; nt++){
      float bv = sBout[nt*16 + l15];
      #pragma unroll
      for (int r = 0; r < 4; r++)
        gp[(size_t)(quad*4 + r)*128 + nt*16 + l15] = C[nt][r] + bv;
    }
  }

  // ---- backward: g_h4 = w @ W_out ----
  {
    const float* wr = w + (size_t)(rowBase + l15)*128 + quad*8;
    #pragma unroll
    for (int kt = 0; kt < 4; kt++) a[kt] = cvt8(wr + kt*32);
  }
  gemm16(a, packB + 6*16384, lane, C);

  #pragma unroll
  for (int ii = 0; ii < 4; ii++){
    const int i = 3 - ii;
    __syncthreads();
    #pragma unroll
    for (int nt = 0; nt < 8; nt++)
      #pragma unroll
      for (int r = 0; r < 4; r++)
        ex[(quad*4 + r)*EX_STRIDE + nt*16 + l15] = f2b(C[nt][r]);
    __syncthreads();
    {
      const u16* rp = ex + l15*EX_STRIDE + quad*8;
      #pragma unroll
      for (int kt = 0; kt < 4; kt++) a[kt] = *(const bf16x8*)(rp + kt*32);
    }
    gemm16(a, packB + (7+i)*16384, lane, C);       // g_v = g @ Wl[i]
    // LN backward
    float s1[4] = {0,0,0,0}, s2[4] = {0,0,0,0};
    #pragma unroll
    for (int nt = 0; nt < 8; nt++){
      float g_ = sGam[i*128 + nt*16 + l15];
      #pragma unroll
      for (int r = 0; r < 4; r++){
        float gx = C[nt][r] * g_;                  // g_xhat
        float xh = upk(xhp[i][nt][r>>1], r & 1);
        s1[r] += gx; s2[r] += gx * xh;
        C[nt][r] = gx;
      }
    }
    float m1[4], m2[4];
    #pragma unroll
    for (int r = 0; r < 4; r++){
      m1[r] = rowsum16(s1[r]) * (1.0f/128.0f);
      m2[r] = rowsum16(s2[r]) * (1.0f/128.0f);
    }
    #pragma unroll
    for (int nt = 0; nt < 8; nt++)
      #pragma unroll
      for (int r = 0; r < 4; r++){
        float xh = upk(xhp[i][nt][r>>1], r & 1);
        float sg = upk(sigp[i][nt][r>>1], r & 1);
        float gu = invs[i][r] * (C[nt][r] - m1[r] - xh * m2[r]);
        C[nt][r] = gu * sg;                        // g_a == g_h(prev layer)
      }
  }

  // ---- backward tail: g_p = g @ W_in ; dw = -g_p (direct fp32 store) ----
  __syncthreads();
  #pragma unroll
  for (int nt = 0; nt < 8; nt++)
    #pragma unroll
    for (int r = 0; r < 4; r++)
      ex[(quad*4 + r)*EX_STRIDE + nt*16 + l15] = f2b(C[nt][r]);
  __syncthreads();
  {
    const u16* rp = ex + l15*EX_STRIDE + quad*8;
    #pragma unroll
    for (int kt = 0; kt < 4; kt++) a[kt] = *(const bf16x8*)(rp + kt*32);
  }
  gemm16(a, packB + 11*16384, lane, C);
  {
    float* gp = dw_out + (size_t)rowBase*128;
    #pragma unroll
    for (int nt = 0; nt < 8; nt++)
      #pragma unroll
      for (int r = 0; r < 4; r++)
        gp[(size_t)(quad*4 + r)*128 + nt*16 + l15] = -C[nt][r];
  }
}

extern "C" void kernel_launch(void* const* d_in, const int* in_sizes, int n_in,
                              void* d_out, int out_size, void* d_ws, size_t ws_size,
                              hipStream_t stream)
{
  const float* t     = (const float*)d_in[0];
  const float* p     = (const float*)d_in[1];
  const float* w     = (const float*)d_in[2];
  const float* W_in  = (const float*)d_in[3];
  const float* b_in  = (const float*)d_in[4];
  const float* fw    = (const float*)d_in[5];
  const float* fb    = (const float*)d_in[6];
  const float* gamma = (const float*)d_in[7];
  const float* beta  = (const float*)d_in[8];
  const float* Wl    = (const float*)d_in[9];
  const float* bl    = (const float*)d_in[10];
  const float* W_out = (const float*)d_in[11];
  const float* b_out = (const float*)d_in[12];

  u16*   packB = (u16*)d_ws;                           // 12*16384 bf16 = 384 KiB
  float* vecs  = (float*)((char*)d_ws + 12*16384*2);   // 2304 fp32

  prep_kernel<<<777, 256, 0, stream>>>(t, W_in, b_in, fw, fb, gamma, beta,
                                       Wl, bl, W_out, b_out, packB, vecs);

  float* dp = (float*)d_out;
  float* dw = (float*)d_out + (size_t)NB * 128;
  fused_vf<<<NB/64, 256, 0, stream>>>(p, w, packB, vecs, dp, dw);
}

// Round 3
// 577.426 us; speedup vs baseline: 2.0379x; 2.0379x over previous
//
#include <hip/hip_runtime.h>

typedef unsigned short u16;
typedef unsigned int   u32;
typedef __attribute__((ext_vector_type(8))) short bf16x8;
typedef __attribute__((ext_vector_type(4))) float f32x4;

#define NB 131072               // batch rows
#define LN_EPS 1e-5f
#define EX_STRIDE 136           // 128 + 8 pad (bf16 elems) -> 2-way bank alias only (free, m136)

__device__ __forceinline__ u16 f2b(float f){
  union { float f; u32 u; } c; c.f = f;
  u32 r = c.u + 0x7FFFu + ((c.u >> 16) & 1u);   // RNE fp32->bf16
  return (u16)(r >> 16);
}
__device__ __forceinline__ float upk(u32 pr, int hi){
  union { u32 u; float f; } c; c.u = hi ? (pr & 0xFFFF0000u) : (pr << 16); return c.f;
}
__device__ __forceinline__ float rowsum16(float x){
  // masks 1,2,4,8 stay inside the 16-lane group holding one C-layout row
  x += __shfl_xor(x, 1);
  x += __shfl_xor(x, 2);
  x += __shfl_xor(x, 4);
  x += __shfl_xor(x, 8);
  return x;
}
// 8 consecutive fp32 -> bf16x8 A-fragment chunk
__device__ __forceinline__ bf16x8 cvt8(const float* __restrict__ s){
  f32x4 x0 = *(const f32x4*)s;
  f32x4 x1 = *(const f32x4*)(s + 4);
  bf16x8 r;
  r[0]=(short)f2b(x0[0]); r[1]=(short)f2b(x0[1]);
  r[2]=(short)f2b(x0[2]); r[3]=(short)f2b(x0[3]);
  r[4]=(short)f2b(x1[0]); r[5]=(short)f2b(x1[1]);
  r[6]=(short)f2b(x1[2]); r[7]=(short)f2b(x1[3]);
  return r;
}

// 16x128 @ 128x128 GEMM: A frags (4 K-tiles) vs pre-packed B fragments in ws.
__device__ __forceinline__ void gemm16(const bf16x8 a[4], const u16* __restrict__ Bmat,
                                       int lane, f32x4 C[8]){
  const bf16x8* Bf = (const bf16x8*)Bmat;
  #pragma unroll
  for (int nt = 0; nt < 8; nt++){
    f32x4 c = {0.f, 0.f, 0.f, 0.f};
    #pragma unroll
    for (int kt = 0; kt < 4; kt++){
      bf16x8 b = Bf[(nt*4 + kt)*64 + lane];
      c = __builtin_amdgcn_mfma_f32_16x16x32_bf16(a[kt], b, c, 0, 0, 0);
    }
    C[nt] = c;
  }
}

// ---------------- prep: pack weights (fp32 -> bf16) into B-fragment order + fp32 vectors ----
// packB layout: mat m (0..11), fragment fi = nt*4+kt, lane, j:
//   packB[m*16384 + fi*512 + lane*8 + j] = Bg[k][n],  k = kt*32+(lane>>4)*8+j, n = nt*16+(lane&15)
// mats 0..5 (fwd, X @ W^T):  Bg[k][n] = src[n*128+k]
// mats 6..11 (bwd, G @ W):   Bg[k][n] = src[k*128+n]
__global__ void prep_kernel(const float* __restrict__ t,   const float* __restrict__ W_in,
                            const float* __restrict__ b_in,const float* __restrict__ fw,
                            const float* __restrict__ fb,  const float* __restrict__ gamma,
                            const float* __restrict__ beta,const float* __restrict__ Wl,
                            const float* __restrict__ bl,  const float* __restrict__ W_out,
                            const float* __restrict__ b_out,
                            u16* __restrict__ packB, float* __restrict__ vecs)
{
  int bid = blockIdx.x, tid = threadIdx.x;
  if (bid < 768){
    int e    = bid*256 + tid;       // 0..196607
    int m    = e >> 14;             // matrix 0..11
    int r    = e & 16383;
    int fi   = r >> 9;              // nt*4+kt
    int lane = (r >> 3) & 63;
    int j    = r & 7;
    int nt = fi >> 2, kt = fi & 3;
    int k = kt*32 + (lane >> 4)*8 + j;
    int n = nt*16 + (lane & 15);
    const float* src; bool tr;
    if      (m == 0){ src = W_in;              tr = true;  }
    else if (m <= 4){ src = Wl + (m-1)*16384;  tr = true;  }
    else if (m == 5){ src = W_out;             tr = true;  }
    else if (m == 6){ src = W_out;             tr = false; }
    else if (m <=10){ src = Wl + (m-7)*16384;  tr = false; }
    else            { src = W_in;              tr = false; }
    packB[e] = f2b(tr ? src[n*128 + k] : src[k*128 + n]);
  } else {
    int idx = (bid - 768)*256 + tid;   // 0..2303
    float tv = t[0];
    float v;
    if      (idx <  512) v = sinf(tv * fw[idx] + fb[idx]);
    else if (idx <  640) v = b_in[idx - 512];
    else if (idx < 1152) v = bl[idx - 640];
    else if (idx < 1664) v = gamma[idx - 1152];
    else if (idx < 2176) v = beta[idx - 1664];
    else                 v = b_out[idx - 2176];
    vecs[idx] = v;
  }
}

// ---------------- fused forward + VJP ----------------
// Checkpoint strategy (round 3): store only a_i (pre-activation, bf16-packed; 64 regs)
// plus mu/inv_std fp32 (32 regs). Backward recomputes sp/xh/sig:
//   e = exp(-|a|); sp = max(a,0)+log1p(e); xh = (sp-mu)*inv; sig = exp(a-sp).
// Keeps per-thread state ~180 unified regs < 256 (2 waves/EU) -> no scratch spill.
__global__ __launch_bounds__(256, 2)
void fused_vf(const float* __restrict__ p, const float* __restrict__ w,
              const u16* __restrict__ packB, const float* __restrict__ vecs,
              float* __restrict__ dp_out, float* __restrict__ dw_out)
{
  __shared__ __align__(16) u16  exch[4 * 16 * EX_STRIDE];
  __shared__ float sv[2304];

  const int tid  = threadIdx.x;
  const int wave = tid >> 6, lane = tid & 63;
  const int l15  = lane & 15, quad = lane >> 4;
  u16* ex = exch + wave * 16 * EX_STRIDE;

  for (int idx = tid; idx < 2304; idx += 256) sv[idx] = vecs[idx];
  __syncthreads();
  const float* sS    = sv;          // [4][128] sin embed
  const float* sBin  = sv + 512;    // [128]
  const float* sBl   = sv + 640;    // [4][128]
  const float* sGam  = sv + 1152;   // [4][128]
  const float* sBet  = sv + 1664;   // [4][128]
  const float* sBout = sv + 2176;   // [128]

  const long rowBase = (long)blockIdx.x * 64 + wave * 16;

  // backward checkpoints
  u32   ap[4][8][2];     // a_i bf16-packed along C reg dim (64 regs)
  float mus[4][4];       // LN mean per (layer, reg-row)
  float invs[4][4];      // LN inv-std

  bf16x8 a[4];
  f32x4  C[8];

  // ---- forward: h0 = p @ W_in^T + b_in ----
  {
    const float* pr = p + (size_t)(rowBase + l15)*128 + quad*8;
    #pragma unroll
    for (int kt = 0; kt < 4; kt++) a[kt] = cvt8(pr + kt*32);
  }
  gemm16(a, packB + 0*16384, lane, C);
  #pragma unroll
  for (int nt = 0; nt < 8; nt++){
    float bv = sBin[nt*16 + l15];
    #pragma unroll
    for (int r = 0; r < 4; r++) C[nt][r] += bv;
  }

  // ---- forward layers ----
  #pragma unroll
  for (int i = 0; i < 4; i++){
    float sum[4] = {0,0,0,0}, ssq[4] = {0,0,0,0};
    #pragma unroll
    for (int nt = 0; nt < 8; nt++){
      float se = sS[i*128 + nt*16 + l15];
      #pragma unroll
      for (int r = 0; r < 4; r++){
        float x  = C[nt][r] + se;                 // a_i
        u16 ab = f2b(x);
        if (r & 1) ap[i][nt][r>>1] |= ((u32)ab) << 16; else ap[i][nt][r>>1] = ab;
        float e  = __expf(-fabsf(x));
        float li = __logf(1.0f + e);
        float sp = fmaxf(x, 0.0f) + li;           // softplus
        sum[r] += sp; ssq[r] += sp*sp;
        C[nt][r] = sp;                            // u_i in place
      }
    }
    float mu[4], inv[4];
    #pragma unroll
    for (int r = 0; r < 4; r++){
      float m1 = rowsum16(sum[r]) * (1.0f/128.0f);
      float m2 = rowsum16(ssq[r]) * (1.0f/128.0f);
      float var = m2 - m1*m1;
      mu[r] = m1; inv[r] = rsqrtf(fmaxf(var, 0.0f) + LN_EPS);
      mus[i][r] = m1; invs[i][r] = inv[r];
    }
    __syncthreads();
    #pragma unroll
    for (int nt = 0; nt < 8; nt++){
      float g_ = sGam[i*128 + nt*16 + l15];
      float b_ = sBet[i*128 + nt*16 + l15];
      #pragma unroll
      for (int r = 0; r < 4; r++){
        float xh = (C[nt][r] - mu[r]) * inv[r];
        float v = xh * g_ + b_;
        ex[(quad*4 + r)*EX_STRIDE + nt*16 + l15] = f2b(v);
      }
    }
    __syncthreads();
    {
      const u16* rp = ex + l15*EX_STRIDE + quad*8;
      #pragma unroll
      for (int kt = 0; kt < 4; kt++) a[kt] = *(const bf16x8*)(rp + kt*32);
    }
    gemm16(a, packB + (1+i)*16384, lane, C);
    #pragma unroll
    for (int nt = 0; nt < 8; nt++){
      float bv = sBl[i*128 + nt*16 + l15];
      #pragma unroll
      for (int r = 0; r < 4; r++) C[nt][r] += bv;
    }
  }

  // ---- forward head: dp = h4 @ W_out^T + b_out (direct fp32 C-layout store) ----
  __syncthreads();
  #pragma unroll
  for (int nt = 0; nt < 8; nt++)
    #pragma unroll
    for (int r = 0; r < 4; r++)
      ex[(quad*4 + r)*EX_STRIDE + nt*16 + l15] = f2b(C[nt][r]);
  __syncthreads();
  {
    const u16* rp = ex + l15*EX_STRIDE + quad*8;
    #pragma unroll
    for (int kt = 0; kt < 4; kt++) a[kt] = *(const bf16x8*)(rp + kt*32);
  }
  gemm16(a, packB + 5*16384, lane, C);
  {
    float* gp = dp_out + (size_t)rowBase*128;
    #pragma unroll
    for (int nt = 0; nt < 8; nt++){
      float bv = sBout[nt*16 + l15];
      #pragma unroll
      for (int r = 0; r < 4; r++)
        gp[(size_t)(quad*4 + r)*128 + nt*16 + l15] = C[nt][r] + bv;
    }
  }

  // ---- backward: g_h4 = w @ W_out ----
  {
    const float* wr = w + (size_t)(rowBase + l15)*128 + quad*8;
    #pragma unroll
    for (int kt = 0; kt < 4; kt++) a[kt] = cvt8(wr + kt*32);
  }
  gemm16(a, packB + 6*16384, lane, C);

  #pragma unroll
  for (int ii = 0; ii < 4; ii++){
    const int i = 3 - ii;
    __syncthreads();
    #pragma unroll
    for (int nt = 0; nt < 8; nt++)
      #pragma unroll
      for (int r = 0; r < 4; r++)
        ex[(quad*4 + r)*EX_STRIDE + nt*16 + l15] = f2b(C[nt][r]);
    __syncthreads();
    {
      const u16* rp = ex + l15*EX_STRIDE + quad*8;
      #pragma unroll
      for (int kt = 0; kt < 4; kt++) a[kt] = *(const bf16x8*)(rp + kt*32);
    }
    gemm16(a, packB + (7+i)*16384, lane, C);       // g_v = g @ Wl[i]
    // LN backward (recompute xh from a-checkpoint)
    float s1[4] = {0,0,0,0}, s2[4] = {0,0,0,0};
    #pragma unroll
    for (int nt = 0; nt < 8; nt++){
      float g_ = sGam[i*128 + nt*16 + l15];
      #pragma unroll
      for (int r = 0; r < 4; r++){
        float a_ = upk(ap[i][nt][r>>1], r & 1);
        float e  = __expf(-fabsf(a_));
        float sp = fmaxf(a_, 0.0f) + __logf(1.0f + e);
        float xh = (sp - mus[i][r]) * invs[i][r];
        float gx = C[nt][r] * g_;                  // g_xhat
        s1[r] += gx; s2[r] += gx * xh;
        C[nt][r] = gx;
      }
    }
    float m1[4], m2[4];
    #pragma unroll
    for (int r = 0; r < 4; r++){
      m1[r] = rowsum16(s1[r]) * (1.0f/128.0f);
      m2[r] = rowsum16(s2[r]) * (1.0f/128.0f);
    }
    #pragma unroll
    for (int nt = 0; nt < 8; nt++)
      #pragma unroll
      for (int r = 0; r < 4; r++){
        float a_ = upk(ap[i][nt][r>>1], r & 1);
        float e  = __expf(-fabsf(a_));
        float sp = fmaxf(a_, 0.0f) + __logf(1.0f + e);
        float xh = (sp - mus[i][r]) * invs[i][r];
        float sg = __expf(a_ - sp);                // sigmoid(a) = exp(a - softplus(a))
        float gu = invs[i][r] * (C[nt][r] - m1[r] - xh * m2[r]);
        C[nt][r] = gu * sg;                        // g_a == g_h(prev layer)
      }
  }

  // ---- backward tail: g_p = g @ W_in ; dw = -g_p (direct fp32 store) ----
  __syncthreads();
  #pragma unroll
  for (int nt = 0; nt < 8; nt++)
    #pragma unroll
    for (int r = 0; r < 4; r++)
      ex[(quad*4 + r)*EX_STRIDE + nt*16 + l15] = f2b(C[nt][r]);
  __syncthreads();
  {
    const u16* rp = ex + l15*EX_STRIDE + quad*8;
    #pragma unroll
    for (int kt = 0; kt < 4; kt++) a[kt] = *(const bf16x8*)(rp + kt*32);
  }
  gemm16(a, packB + 11*16384, lane, C);
  {
    float* gp = dw_out + (size_t)rowBase*128;
    #pragma unroll
    for (int nt = 0; nt < 8; nt++)
      #pragma unroll
      for (int r = 0; r < 4; r++)
        gp[(size_t)(quad*4 + r)*128 + nt*16 + l15] = -C[nt][r];
  }
}

extern "C" void kernel_launch(void* const* d_in, const int* in_sizes, int n_in,
                              void* d_out, int out_size, void* d_ws, size_t ws_size,
                              hipStream_t stream)
{
  const float* t     = (const float*)d_in[0];
  const float* p     = (const float*)d_in[1];
  const float* w     = (const float*)d_in[2];
  const float* W_in  = (const float*)d_in[3];
  const float* b_in  = (const float*)d_in[4];
  const float* fw    = (const float*)d_in[5];
  const float* fb    = (const float*)d_in[6];
  const float* gamma = (const float*)d_in[7];
  const float* beta  = (const float*)d_in[8];
  const float* Wl    = (const float*)d_in[9];
  const float* bl    = (const float*)d_in[10];
  const float* W_out = (const float*)d_in[11];
  const float* b_out = (const float*)d_in[12];

  u16*   packB = (u16*)d_ws;                           // 12*16384 bf16 = 384 KiB
  float* vecs  = (float*)((char*)d_ws + 12*16384*2);   // 2304 fp32

  prep_kernel<<<777, 256, 0, stream>>>(t, W_in, b_in, fw, fb, gamma, beta,
                                       Wl, bl, W_out, b_out, packB, vecs);

  float* dp = (float*)d_out;
  float* dw = (float*)d_out + (size_t)NB * 128;
  fused_vf<<<NB/64, 256, 0, stream>>>(p, w, packB, vecs, dp, dw);
}